// Round 5
// baseline (77.611 us; speedup 1.0000x reference)
//
#include <hip/hip_runtime.h>
#include <math.h>

#define NB 4
#define NT 128
#define NS 512
#define NH 256

__device__ __forceinline__ float fast_tanh(float x) {
    // tanh(x) = 1 - 2/(exp(2x)+1); safe at +/-inf
    float e = __expf(2.0f * x);
    return 1.0f - 2.0f / (e + 1.0f);
}

// 1/(e^z + 1): 2 trans ops (exp + rcp)
__device__ __forceinline__ float sigm_neg(float z) {
    return __builtin_amdgcn_rcpf(__expf(z) + 1.0f);
}

__device__ __forceinline__ float dot4(float4 a, float4 b, float acc) {
    acc = fmaf(a.x, b.x, acc);
    acc = fmaf(a.y, b.y, acc);
    acc = fmaf(a.z, b.z, acc);
    acc = fmaf(a.w, b.w, acc);
    return acc;
}

// ---------------------------------------------------------------------------
// K_A, one launch, roles by blockIdx.x:
//   [0,256):   pe' = 2*(enc . Wh^T)          (2048 rows)
//   [256,320): pq' = 2*(q . Ws^T)            (512 rows); block 256 also w=-2v
//   [320,384): oq  = q . W1^T  (W1 = Wout[:, :256])
//   [384,400): W2T[k][o] = Wout[o][256+k]    (64x64 LDS transpose tiles)
// GEMM template: weight tile (64 o x 256 k) LDS-staged XOR-swizzled; X rows
// wave-uniform (s_load); coalesced writes. 8 waves x 4 m-rows.
// ---------------------------------------------------------------------------
__global__ __launch_bounds__(512) void kA(
    const float* __restrict__ enc, const float* __restrict__ q,
    const float* __restrict__ Wh, const float* __restrict__ Ws,
    const float* __restrict__ Wout, const float* __restrict__ v,
    float* __restrict__ pe, float* __restrict__ pq,
    float* __restrict__ oq, float* __restrict__ w2t, float* __restrict__ w)
{
    __shared__ float4 wsh[64 * 64];   // 64 KB
    const int bx = blockIdx.x;
    const int tid = threadIdx.x;

    if (bx >= 384) {
        // ---- transpose W2 -> w2t, 64x64 tiles, pad 65 to spread banks ----
        float* tl = reinterpret_cast<float*>(wsh);
        const int bi = bx - 384;
        const int oi = bi & 3, ki = bi >> 2;
        {
            const int row = tid >> 3;     // o-local
            const int jl  = tid & 7;
            const float4* src = reinterpret_cast<const float4*>(
                Wout + (size_t)(oi * 64 + row) * (2 * NH) + NH + ki * 64);
#pragma unroll
            for (int e2 = 0; e2 < 2; ++e2) {
                const int j = jl * 2 + e2;        // f4 idx along k-local
                const float4 val = src[j];
                tl[(j * 4 + 0) * 65 + row] = val.x;
                tl[(j * 4 + 1) * 65 + row] = val.y;
                tl[(j * 4 + 2) * 65 + row] = val.z;
                tl[(j * 4 + 3) * 65 + row] = val.w;
            }
        }
        __syncthreads();
        {
            const int row = tid >> 3;     // k-local
            const int jl  = tid & 7;
#pragma unroll
            for (int e2 = 0; e2 < 2; ++e2) {
                const int j = jl * 2 + e2;        // f4 idx along o-local
                float4 val;
                val.x = tl[row * 65 + j * 4 + 0];
                val.y = tl[row * 65 + j * 4 + 1];
                val.z = tl[row * 65 + j * 4 + 2];
                val.w = tl[row * 65 + j * 4 + 3];
                reinterpret_cast<float4*>(
                    w2t + (size_t)(ki * 64 + row) * NH + oi * 64)[j] = val;
            }
        }
        return;
    }

    const float* X; const float* W; float* dst;
    int r0, wstride, ot; float scale;
    if (bx < 256) {
        const int mt = bx >> 2; ot = bx & 3;
        X = enc; W = Wh; dst = pe; r0 = mt * 32; wstride = NH; scale = 2.f;
    } else if (bx < 320) {
        const int b2 = bx - 256; const int mt = b2 >> 2; ot = b2 & 3;
        X = q; W = Ws; dst = pq; r0 = mt * 32; wstride = NH; scale = 2.f;
        if (bx == 256 && tid < NH) w[tid] = -2.f * v[tid];
    } else {
        const int b3 = bx - 320; const int mt = b3 >> 2; ot = b3 & 3;
        X = q; W = Wout; dst = oq; r0 = mt * 32; wstride = 2 * NH; scale = 1.f;
    }

    // stage W tile: 64 rows x 64 f4, XOR-swizzled low-3
    {
        const int row = tid >> 3, jl = tid & 7;
        const float4* src = reinterpret_cast<const float4*>(W + (size_t)(ot * 64 + row) * wstride);
        const int rsw = row & 7;
#pragma unroll
        for (int kk = 0; kk < 8; ++kk) {
            const int j = jl + 8 * kk;
            wsh[row * 64 + (j ^ rsw)] = src[j];
        }
    }
    __syncthreads();

    const int o  = tid & 63;
    const int wv = __builtin_amdgcn_readfirstlane(tid >> 6);
    const int m0 = r0 + wv * 4;

    const float4* __restrict__ x0 = reinterpret_cast<const float4*>(X + (size_t)(m0 + 0) * NH);
    const float4* __restrict__ x1 = reinterpret_cast<const float4*>(X + (size_t)(m0 + 1) * NH);
    const float4* __restrict__ x2 = reinterpret_cast<const float4*>(X + (size_t)(m0 + 2) * NH);
    const float4* __restrict__ x3 = reinterpret_cast<const float4*>(X + (size_t)(m0 + 3) * NH);

    float a0 = 0.f, a1 = 0.f, a2 = 0.f, a3 = 0.f;
    const int osw = o & 7;
#pragma unroll 8
    for (int k4 = 0; k4 < 64; ++k4) {
        const float4 wq = wsh[o * 64 + (k4 ^ osw)];
        a0 = dot4(wq, x0[k4], a0);
        a1 = dot4(wq, x1[k4], a1);
        a2 = dot4(wq, x2[k4], a2);
        a3 = dot4(wq, x3[k4], a3);
    }
    const int oc = ot * 64 + o;
    dst[(size_t)(m0 + 0) * NH + oc] = a0 * scale;
    dst[(size_t)(m0 + 1) * NH + oc] = a1 * scale;
    dst[(size_t)(m0 + 2) * NH + oc] = a2 * scale;
    dst[(size_t)(m0 + 3) * NH + oc] = a3 * scale;
}

// ---------------------------------------------------------------------------
// K_B: per (b, 2 t-rows): scores (8 chunked pe tiles via LDS) -> masked
// softmax (in-register, waves 0-1) -> context (coalesced enc) -> c.W2T + oq
// + tanh. 512 thr, ~70KB LDS -> 2 blocks/CU. Grid (64 t-tiles, 4 b) = 256.
// All reductions fixed-order (deterministic).
// ---------------------------------------------------------------------------
__global__ __launch_bounds__(512) void kB(
    const float* __restrict__ enc, const int* __restrict__ lens,
    const float* __restrict__ pe, const float* __restrict__ pq,
    const float* __restrict__ w, const float* __restrict__ w2t,
    const float* __restrict__ oq, float* __restrict__ out)
{
    __shared__ __align__(16) float4 buf4[64 * 64];   // 64 KB; aliased later
    __shared__ __align__(16) float eacc[2][NS];      // 4 KB: e' rows -> alpha
    __shared__ float e_part[4][2][64];               // 2 KB
    __shared__ float rs_sh[2];

    float*  alias  = reinterpret_cast<float*>(buf4);
    float*  c_part = alias;                               // [sh][t][h] 4 KB
    float*  c_sh   = alias + 1024;                        // [t][h]     2 KB
    float4* opart  = reinterpret_cast<float4*>(alias + 2048); // [kq][t][o4] 8 KB

    const int tt  = blockIdx.x;       // 0..63
    const int b   = blockIdx.y;
    const int t0  = tt * 2;
    const int tid = threadIdx.x;
    const int len = lens[b];

    const float* peb = pe + (size_t)b * NS * NH;

    // ---- phase 1: scores e'[t,s] = sum_h w[h]*sigm_neg(pe'[s,h]+pq'[t,h]) ----
    const int s_l = tid & 63;
    const int t_i = (tid >> 6) & 1;   // wave-uniform
    const int u   = tid >> 7;         // h-quarter, wave-uniform
    const float4* __restrict__ pq4 = reinterpret_cast<const float4*>(
        pq + (size_t)(b * NT + t0 + t_i) * NH);
    const float4* __restrict__ w4 = reinterpret_cast<const float4*>(w);

    const int srow = tid >> 3, sjl = tid & 7, srsw = srow & 7;
    const int ssw = s_l & 7;

    for (int sx = 0; sx < 8; ++sx) {
        // stage pe chunk (64 s-rows x 256 h), swizzled
        {
            const float4* src = reinterpret_cast<const float4*>(
                peb + (size_t)(sx * 64 + srow) * NH);
#pragma unroll
            for (int kk = 0; kk < 8; ++kk) {
                const int j = sjl + 8 * kk;
                buf4[srow * 64 + (j ^ srsw)] = src[j];
            }
        }
        __syncthreads();
        {
            float acc = 0.f;
#pragma unroll
            for (int j = 0; j < 16; ++j) {
                const int jj = u * 16 + j;
                const float4 pv = buf4[s_l * 64 + (jj ^ ssw)];
                const float4 aq = pq4[jj];
                const float4 wv = w4[jj];
                acc = fmaf(wv.x, sigm_neg(pv.x + aq.x), acc);
                acc = fmaf(wv.y, sigm_neg(pv.y + aq.y), acc);
                acc = fmaf(wv.z, sigm_neg(pv.z + aq.z), acc);
                acc = fmaf(wv.w, sigm_neg(pv.w + aq.w), acc);
            }
            e_part[u][t_i][s_l] = acc;
        }
        __syncthreads();
        if (tid < 128) {   // deterministic partial reduce, write-once per s
            const int t = tid >> 6, sl = tid & 63;
            eacc[t][sx * 64 + sl] = e_part[0][t][sl] + e_part[1][t][sl]
                                  + e_part[2][t][sl] + e_part[3][t][sl];
        }
    }
    __syncthreads();

    // ---- phase 2: masked softmax, waves 0-1 (one t-row each), in-register ----
    const int wave = tid >> 6, lane = tid & 63;
    if (wave < 2) {
        const int t = wave;
        float vals[8];
        float m = -INFINITY;
#pragma unroll
        for (int k = 0; k < 8; ++k) {
            float e0 = eacc[t][lane + 64 * k];
            if (lane + 64 * k >= len) e0 = -INFINITY;
            vals[k] = e0;
            m = fmaxf(m, e0);
        }
#pragma unroll
        for (int off = 32; off; off >>= 1) m = fmaxf(m, __shfl_xor(m, off));
        float sum = 0.f;
#pragma unroll
        for (int k = 0; k < 8; ++k) {
            const float p = __expf(vals[k] - m);   // exp(-inf)=0 for masked
            sum += p;
            eacc[t][lane + 64 * k] = p;            // unnormalized alpha
        }
#pragma unroll
        for (int off = 32; off; off >>= 1) sum += __shfl_xor(sum, off);
        if (lane == 0) rs_sh[t] = 1.0f / sum;
    }
    __syncthreads();

    // ---- phase 3: context, thread = (h 0..255, s-half); coalesced enc ----
    {
        const int h  = tid & 255;
        const int sh = tid >> 8;
        const float* ep = enc + (size_t)b * NS * NH + (size_t)(sh * 256) * NH + h;
        const float4* a0 = reinterpret_cast<const float4*>(&eacc[0][sh * 256]);
        const float4* a1 = reinterpret_cast<const float4*>(&eacc[1][sh * 256]);
        float cA = 0.f, cB = 0.f;
#pragma unroll 4
        for (int s4 = 0; s4 < 64; ++s4) {
            const float4 pa = a0[s4];
            const float4 pb = a1[s4];
            const float* eb = ep + (size_t)(4 * s4) * NH;
            const float x0 = eb[0], x1 = eb[NH], x2 = eb[2 * NH], x3 = eb[3 * NH];
            cA = fmaf(pa.x, x0, cA); cA = fmaf(pa.y, x1, cA);
            cA = fmaf(pa.z, x2, cA); cA = fmaf(pa.w, x3, cA);
            cB = fmaf(pb.x, x0, cB); cB = fmaf(pb.y, x1, cB);
            cB = fmaf(pb.z, x2, cB); cB = fmaf(pb.w, x3, cB);
        }
        c_part[(sh * 2 + 0) * NH + h] = cA;
        c_part[(sh * 2 + 1) * NH + h] = cB;
    }
    __syncthreads();
    {
        const int h = tid & 255, t = tid >> 8;
        c_sh[t * NH + h] = (c_part[(0 + t) * NH + h] + c_part[(2 + t) * NH + h]) * rs_sh[t];
    }
    __syncthreads();

    // ---- phase 4: out = tanh(oq + c.W2T); thread = (o4, t, kq) ----
    {
        const int o4 = tid & 63;
        const int t  = (tid >> 6) & 1;
        const int kq = tid >> 7;
        const float4* __restrict__ w2t4 = reinterpret_cast<const float4*>(w2t);
        const float4* cs4 = reinterpret_cast<const float4*>(&c_sh[t * NH]);
        float4 acc = make_float4(0.f, 0.f, 0.f, 0.f);
#pragma unroll 4
        for (int j4 = 0; j4 < 16; ++j4) {
            const int k0 = kq * 64 + j4 * 4;
            const float4 cv = cs4[kq * 16 + j4];
            float4 wr;
            wr = w2t4[(size_t)(k0 + 0) * 64 + o4];
            acc.x = fmaf(cv.x, wr.x, acc.x); acc.y = fmaf(cv.x, wr.y, acc.y);
            acc.z = fmaf(cv.x, wr.z, acc.z); acc.w = fmaf(cv.x, wr.w, acc.w);
            wr = w2t4[(size_t)(k0 + 1) * 64 + o4];
            acc.x = fmaf(cv.y, wr.x, acc.x); acc.y = fmaf(cv.y, wr.y, acc.y);
            acc.z = fmaf(cv.y, wr.z, acc.z); acc.w = fmaf(cv.y, wr.w, acc.w);
            wr = w2t4[(size_t)(k0 + 2) * 64 + o4];
            acc.x = fmaf(cv.z, wr.x, acc.x); acc.y = fmaf(cv.z, wr.y, acc.y);
            acc.z = fmaf(cv.z, wr.z, acc.z); acc.w = fmaf(cv.z, wr.w, acc.w);
            wr = w2t4[(size_t)(k0 + 3) * 64 + o4];
            acc.x = fmaf(cv.w, wr.x, acc.x); acc.y = fmaf(cv.w, wr.y, acc.y);
            acc.z = fmaf(cv.w, wr.z, acc.z); acc.w = fmaf(cv.w, wr.w, acc.w);
        }
        opart[(kq * 2 + t) * 64 + o4] = acc;
    }
    __syncthreads();
    if (tid < 128) {
        const int o4 = tid & 63, t = tid >> 6;
        const float4 s0 = opart[(0 + t) * 64 + o4];
        const float4 s1 = opart[(2 + t) * 64 + o4];
        const float4 s2 = opart[(4 + t) * 64 + o4];
        const float4 s3 = opart[(6 + t) * 64 + o4];
        const float4 qo = reinterpret_cast<const float4*>(
            oq + (size_t)(b * NT + t0 + t) * NH)[o4];
        float4 r;
        r.x = fast_tanh(s0.x + s1.x + s2.x + s3.x + qo.x);
        r.y = fast_tanh(s0.y + s1.y + s2.y + s3.y + qo.y);
        r.z = fast_tanh(s0.z + s1.z + s2.z + s3.z + qo.z);
        r.w = fast_tanh(s0.w + s1.w + s2.w + s3.w + qo.w);
        reinterpret_cast<float4*>(out + (size_t)(b * NT + t0 + t) * NH)[o4] = r;
    }
}

extern "C" void kernel_launch(void* const* d_in, const int* in_sizes, int n_in,
                              void* d_out, int out_size, void* d_ws, size_t ws_size,
                              hipStream_t stream) {
    const float* q    = (const float*)d_in[0];  // (B,T,H)
    const float* enc  = (const float*)d_in[1];  // (B,S,H)
    const int*   lens = (const int*)d_in[2];    // (B,)
    const float* Ws   = (const float*)d_in[3];  // (H,H)
    const float* Wh   = (const float*)d_in[4];  // (H,H)
    const float* v    = (const float*)d_in[5];  // (H,)
    const float* Wout = (const float*)d_in[6];  // (H,2H)
    float* out = (float*)d_out;                 // (B,T,H)

    float* pe  = (float*)d_ws;                       // NB*NS*NH
    float* pq  = pe  + (size_t)NB * NS * NH;         // NB*NT*NH
    float* oq  = pq  + (size_t)NB * NT * NH;         // NB*NT*NH
    float* w2t = oq  + (size_t)NB * NT * NH;         // NH*NH
    float* w   = w2t + (size_t)NH * NH;              // NH

    kA<<<400, 512, 0, stream>>>(enc, q, Wh, Ws, Wout, v, pe, pq, oq, w2t, w);
    kB<<<dim3(64, NB), 512, 0, stream>>>(enc, lens, pe, pq, w, w2t, oq, out);
}

// Round 6
// 68.723 us; speedup vs baseline: 1.1293x; 1.1293x over previous
//
#include <hip/hip_runtime.h>
#include <math.h>

#define NB 4
#define NT 128
#define NS 512
#define NH 256

// pe/pq are prescaled by 2*log2(e) so exp(2z) == exp2(pe'+pq')
#define SCALE_2LOG2E 2.8853900817779268f

__device__ __forceinline__ float fast_exp2(float x) {
#if __has_builtin(__builtin_amdgcn_exp2f)
    return __builtin_amdgcn_exp2f(x);
#else
    return __expf(x * 0.6931471805599453f);
#endif
}

__device__ __forceinline__ float fast_tanh(float x) {
    // tanh(x) = 1 - 2/(exp(2x)+1); safe at +/-inf
    float e = __expf(2.0f * x);
    return 1.0f - 2.0f / (e + 1.0f);
}

__device__ __forceinline__ float dot4(float4 a, float4 b, float acc) {
    acc = fmaf(a.x, b.x, acc);
    acc = fmaf(a.y, b.y, acc);
    acc = fmaf(a.z, b.z, acc);
    acc = fmaf(a.w, b.w, acc);
    return acc;
}

// ---------------------------------------------------------------------------
// K1: projections, prescaled by 2*log2e.
//   bx < 256:      peT[b][o][s] = scale*(enc[b,s,:].Wh[o,:])  (transposed via
//                  LDS bounce so K2 reads contiguous s-rows)
//   bx in [256,320): pq[r][o] = scale*(q[r,:].Ws[o,:])  (row-major)
// Template: W tile (64 o x 256 k) LDS-staged XOR-swizzled; X rows
// wave-uniform (s_load). 8 waves x 4 m-rows = 32 rows per block.
// Block 256 also writes w = -2v.
// ---------------------------------------------------------------------------
__global__ __launch_bounds__(512) void k1_proj(
    const float* __restrict__ enc, const float* __restrict__ q,
    const float* __restrict__ Wh, const float* __restrict__ Ws,
    const float* __restrict__ v,
    float* __restrict__ peT, float* __restrict__ pq, float* __restrict__ w)
{
    __shared__ float4 wsh[64 * 64];   // 64 KB
    __shared__ float tl[64 * 36];     // 9 KB transpose bounce (pad 36)

    const int bx = blockIdx.x;
    const int tid = threadIdx.x;
    const bool is_pe = (bx < 256);
    const int mt = is_pe ? (bx >> 2) : ((bx - 256) >> 2);
    const int ot = bx & 3;
    const float* __restrict__ X = is_pe ? enc : q;
    const float* __restrict__ W = is_pe ? Wh : Ws;
    const int r0 = mt * 32;

    if (bx == 256 && tid < NH) w[tid] = -2.0f * v[tid];

    // stage W tile: 64 rows x 64 f4, XOR-swizzled low-3
    {
        const int row = tid >> 3, jl = tid & 7;
        const float4* src = reinterpret_cast<const float4*>(W + (size_t)(ot * 64 + row) * NH);
        const int rsw = row & 7;
#pragma unroll
        for (int kk = 0; kk < 8; ++kk) {
            const int j = jl + 8 * kk;
            wsh[row * 64 + (j ^ rsw)] = src[j];
        }
    }
    __syncthreads();

    const int o  = tid & 63;
    const int wv = __builtin_amdgcn_readfirstlane(tid >> 6);  // 0..7
    const int m0 = r0 + wv * 4;

    const float4* __restrict__ x0 = reinterpret_cast<const float4*>(X + (size_t)(m0 + 0) * NH);
    const float4* __restrict__ x1 = reinterpret_cast<const float4*>(X + (size_t)(m0 + 1) * NH);
    const float4* __restrict__ x2 = reinterpret_cast<const float4*>(X + (size_t)(m0 + 2) * NH);
    const float4* __restrict__ x3 = reinterpret_cast<const float4*>(X + (size_t)(m0 + 3) * NH);

    float a0 = 0.f, a1 = 0.f, a2 = 0.f, a3 = 0.f;
    const int osw = o & 7;
#pragma unroll 8
    for (int k4 = 0; k4 < 64; ++k4) {
        const float4 wq = wsh[o * 64 + (k4 ^ osw)];
        a0 = dot4(wq, x0[k4], a0);
        a1 = dot4(wq, x1[k4], a1);
        a2 = dot4(wq, x2[k4], a2);
        a3 = dot4(wq, x3[k4], a3);
    }

    if (!is_pe) {
        const int oc = ot * 64 + o;
        pq[(size_t)(m0 + 0) * NH + oc] = a0 * SCALE_2LOG2E;
        pq[(size_t)(m0 + 1) * NH + oc] = a1 * SCALE_2LOG2E;
        pq[(size_t)(m0 + 2) * NH + oc] = a2 * SCALE_2LOG2E;
        pq[(size_t)(m0 + 3) * NH + oc] = a3 * SCALE_2LOG2E;
    } else {
        // bounce through LDS to write peT[b][o_global][s] coalesced
        const int ml = wv * 4;                 // m-local 0..31 (s-local)
        tl[o * 36 + ml + 0] = a0 * SCALE_2LOG2E;
        tl[o * 36 + ml + 1] = a1 * SCALE_2LOG2E;
        tl[o * 36 + ml + 2] = a2 * SCALE_2LOG2E;
        tl[o * 36 + ml + 3] = a3 * SCALE_2LOG2E;
        __syncthreads();
        const int row = tid >> 3, jl = tid & 7;   // row = o-local, jl*4 = s-local
        const int b = r0 >> 9, s0 = r0 & (NS - 1);
        const float4 v4 = *reinterpret_cast<const float4*>(&tl[row * 36 + jl * 4]);
        *reinterpret_cast<float4*>(
            peT + ((size_t)b * NH + ot * 64 + row) * NS + s0 + jl * 4) = v4;
    }
}

// ---------------------------------------------------------------------------
// K2: scores (softmax-shift-invariant):
//   e'[t,s] = sum_h w[h] / (exp2(peT[b,h,s] + pq[t,h]) + 1)
// No LDS: waves read peT rows coalesced (block's 8 waves share the same
// 64KB slice -> L1 reuse); pq/w wave-uniform s_loads (t readfirstlane'd).
// Block 512 thr = 8 waves = 8 t-rows; lanes = 64 s. Grid (8 sx, 16 ty, 4 b).
// ---------------------------------------------------------------------------
__global__ __launch_bounds__(512) void k2_score(
    const float* __restrict__ peT, const float* __restrict__ pq,
    const float* __restrict__ w, float* __restrict__ e)
{
    const int sx = blockIdx.x;
    const int ty = blockIdx.y;
    const int b  = blockIdx.z;
    const int lane = threadIdx.x & 63;
    const int wv = __builtin_amdgcn_readfirstlane(threadIdx.x >> 6);
    const int t = ty * 8 + wv;
    const int s = sx * 64 + lane;

    const float4* __restrict__ pqp = reinterpret_cast<const float4*>(
        pq + (size_t)(b * NT + t) * NH);
    const float4* __restrict__ wp = reinterpret_cast<const float4*>(w);
    const float* __restrict__ pp0 = peT + (size_t)b * NH * NS + s;

    float acc = 0.f;
#pragma unroll 4
    for (int h4 = 0; h4 < 64; ++h4) {
        const float4 a  = pqp[h4];
        const float4 wl = wp[h4];
        const float* pp = pp0 + (size_t)(4 * h4) * NS;
        const float p0 = pp[0], p1 = pp[NS], p2 = pp[2 * NS], p3 = pp[3 * NS];
        acc = fmaf(wl.x, __builtin_amdgcn_rcpf(fast_exp2(p0 + a.x) + 1.0f), acc);
        acc = fmaf(wl.y, __builtin_amdgcn_rcpf(fast_exp2(p1 + a.y) + 1.0f), acc);
        acc = fmaf(wl.z, __builtin_amdgcn_rcpf(fast_exp2(p2 + a.z) + 1.0f), acc);
        acc = fmaf(wl.w, __builtin_amdgcn_rcpf(fast_exp2(p3 + a.w) + 1.0f), acc);
    }
    e[(size_t)(b * NT + t) * NS + s] = acc;
}

// ---------------------------------------------------------------------------
// K3: masked softmax + context. Block = 4 independent waves, wave = 1 t-row,
// lanes = 64 h-cols (coalesced enc). Softmax fully in-register; P-row parked
// in LDS for uniform broadcast during context. Grid (4 ht, 32 tt, 4 b).
// ---------------------------------------------------------------------------
__global__ __launch_bounds__(256) void k3_ctx(
    const float* __restrict__ e, const float* __restrict__ enc,
    const int* __restrict__ lens, float* __restrict__ c)
{
    __shared__ float ps[4][NS];

    const int ht = blockIdx.x;
    const int tt = blockIdx.y;
    const int b  = blockIdx.z;
    const int tid  = threadIdx.x;
    const int lane = tid & 63;
    const int wv   = __builtin_amdgcn_readfirstlane(tid >> 6);
    const int t    = tt * 4 + wv;
    const int len  = lens[b];

    const float4* erow = reinterpret_cast<const float4*>(e + (size_t)(b * NT + t) * NS);
    float4 va = erow[lane];
    float4 vb = erow[lane + 64];
    const int c0 = 4 * lane;
    const int c1 = 256 + 4 * lane;
    if (c0 + 0 >= len) va.x = -INFINITY;
    if (c0 + 1 >= len) va.y = -INFINITY;
    if (c0 + 2 >= len) va.z = -INFINITY;
    if (c0 + 3 >= len) va.w = -INFINITY;
    if (c1 + 0 >= len) vb.x = -INFINITY;
    if (c1 + 1 >= len) vb.y = -INFINITY;
    if (c1 + 2 >= len) vb.z = -INFINITY;
    if (c1 + 3 >= len) vb.w = -INFINITY;

    float m = fmaxf(fmaxf(fmaxf(va.x, va.y), fmaxf(va.z, va.w)),
                    fmaxf(fmaxf(vb.x, vb.y), fmaxf(vb.z, vb.w)));
#pragma unroll
    for (int off = 32; off; off >>= 1) m = fmaxf(m, __shfl_xor(m, off));

    va.x = __expf(va.x - m); va.y = __expf(va.y - m);
    va.z = __expf(va.z - m); va.w = __expf(va.w - m);
    vb.x = __expf(vb.x - m); vb.y = __expf(vb.y - m);
    vb.z = __expf(vb.z - m); vb.w = __expf(vb.w - m);

    float sum = va.x + va.y + va.z + va.w + vb.x + vb.y + vb.z + vb.w;
#pragma unroll
    for (int off = 32; off; off >>= 1) sum += __shfl_xor(sum, off);
    const float rsum = 1.0f / sum;

    float4* ps4w = reinterpret_cast<float4*>(&ps[wv][0]);
    ps4w[lane] = va;
    ps4w[lane + 64] = vb;
    __syncthreads();

    const float* ep = enc + (size_t)b * NS * NH + ht * 64 + lane;
    const float4* p4 = reinterpret_cast<const float4*>(&ps[wv][0]);
    float acc0 = 0.f, acc1 = 0.f, acc2 = 0.f, acc3 = 0.f;
#pragma unroll 2
    for (int s4 = 0; s4 < 32; ++s4) {
        {
            const float4 pw = p4[s4];
            const float* eb = ep + (size_t)(4 * s4) * NH;
            acc0 = fmaf(pw.x, eb[0],      acc0);
            acc0 = fmaf(pw.y, eb[NH],     acc0);
            acc0 = fmaf(pw.z, eb[2 * NH], acc0);
            acc0 = fmaf(pw.w, eb[3 * NH], acc0);
        }
        {
            const float4 pw = p4[s4 + 32];
            const float* eb = ep + (size_t)(4 * (s4 + 32)) * NH;
            acc1 = fmaf(pw.x, eb[0],      acc1);
            acc1 = fmaf(pw.y, eb[NH],     acc1);
            acc1 = fmaf(pw.z, eb[2 * NH], acc1);
            acc1 = fmaf(pw.w, eb[3 * NH], acc1);
        }
        {
            const float4 pw = p4[s4 + 64];
            const float* eb = ep + (size_t)(4 * (s4 + 64)) * NH;
            acc2 = fmaf(pw.x, eb[0],      acc2);
            acc2 = fmaf(pw.y, eb[NH],     acc2);
            acc2 = fmaf(pw.z, eb[2 * NH], acc2);
            acc2 = fmaf(pw.w, eb[3 * NH], acc2);
        }
        {
            const float4 pw = p4[s4 + 96];
            const float* eb = ep + (size_t)(4 * (s4 + 96)) * NH;
            acc3 = fmaf(pw.x, eb[0],      acc3);
            acc3 = fmaf(pw.y, eb[NH],     acc3);
            acc3 = fmaf(pw.z, eb[2 * NH], acc3);
            acc3 = fmaf(pw.w, eb[3 * NH], acc3);
        }
    }
    c[(size_t)(b * NT + t) * NH + ht * 64 + lane] =
        (acc0 + acc1 + acc2 + acc3) * rsum;
}

// ---------------------------------------------------------------------------
// K4: out[bt,o] = tanh(cat[bt,:].Wout[o,:]), cat = [q|c]. Lanes = o, Wout
// half-tiles (64 o x 256 k = 64KB) staged swizzled; cat rows wave-uniform
// s_loads. 8 waves = 8 bt rows. Grid 64 bt-tiles x 4 o-tiles = 256 blocks.
// ---------------------------------------------------------------------------
__global__ __launch_bounds__(512) void k4_out(
    const float* __restrict__ qin, const float* __restrict__ cin,
    const float* __restrict__ Wout, float* __restrict__ out)
{
    __shared__ float4 wsh[64 * 64];

    const int ot  = blockIdx.x & 3;
    const int btt = blockIdx.x >> 2;
    const int tid = threadIdx.x;
    const int o   = tid & 63;
    const int wv  = __builtin_amdgcn_readfirstlane(tid >> 6);
    const int bt  = btt * 8 + wv;
    const int osw = o & 7;

    float acc = 0.f;
#pragma unroll
    for (int half = 0; half < 2; ++half) {
        __syncthreads();
        {
            const int row = tid >> 3, jl = tid & 7;
            const float4* src = reinterpret_cast<const float4*>(
                Wout + (size_t)(ot * 64 + row) * (2 * NH) + half * NH);
            const int rsw = row & 7;
#pragma unroll
            for (int kk = 0; kk < 8; ++kk) {
                const int j = jl + 8 * kk;
                wsh[row * 64 + (j ^ rsw)] = src[j];
            }
        }
        __syncthreads();

        const float4* __restrict__ xr = reinterpret_cast<const float4*>(
            (half ? cin : qin) + (size_t)bt * NH);
#pragma unroll 8
        for (int k4 = 0; k4 < 64; ++k4) {
            acc = dot4(wsh[o * 64 + (k4 ^ osw)], xr[k4], acc);
        }
    }
    out[(size_t)bt * NH + ot * 64 + o] = fast_tanh(acc);
}

extern "C" void kernel_launch(void* const* d_in, const int* in_sizes, int n_in,
                              void* d_out, int out_size, void* d_ws, size_t ws_size,
                              hipStream_t stream) {
    const float* q    = (const float*)d_in[0];  // (B,T,H)
    const float* enc  = (const float*)d_in[1];  // (B,S,H)
    const int*   lens = (const int*)d_in[2];    // (B,)
    const float* Ws   = (const float*)d_in[3];  // (H,H)
    const float* Wh   = (const float*)d_in[4];  // (H,H)
    const float* v    = (const float*)d_in[5];  // (H,)
    const float* Wout = (const float*)d_in[6];  // (H,2H)
    float* out = (float*)d_out;                 // (B,T,H)

    float* peT = (float*)d_ws;                        // NB*NH*NS
    float* pq  = peT + (size_t)NB * NH * NS;          // NB*NT*NH
    float* w   = pq  + (size_t)NB * NT * NH;          // NH
    float* e   = w + NH;                              // NB*NT*NS
    float* c   = e + (size_t)NB * NT * NS;            // NB*NT*NH

    k1_proj<<<320, 512, 0, stream>>>(enc, q, Wh, Ws, v, peT, pq, w);
    k2_score<<<dim3(NS / 64, NT / 8, NB), 512, 0, stream>>>(peT, pq, w, e);
    k3_ctx<<<dim3(NH / 64, NT / 4, NB), 256, 0, stream>>>(e, enc, lens, c);
    k4_out<<<256, 512, 0, stream>>>(q, c, Wout, out);
}